// Round 3
// baseline (3262.522 us; speedup 1.0000x reference)
//
#include <hip/hip_runtime.h>
#include <hip/hip_fp16.h>

#define T_DIM 2048
#define B_DIM 64
#define I_DIM 128
#define H_DIM 256
#define L_DIM 6
#define C_DIM 100
#define M_DIM (T_DIM * B_DIM)   // 131072 rows
#define S_DIM (B_DIM * H_DIM)   // 16384 chains

typedef unsigned short u16;
typedef unsigned int   u32;

__device__ __forceinline__ float h2f(u16 u) { return __half2float(__ushort_as_half(u)); }
__device__ __forceinline__ u16   f2h(float f) { return __half_as_ushort(__float2half(f)); }

// ---------------- layer-0 GEMM: Y[M,256] = x[M,128] @ W0[128,256] + b0 (fp16 out)
__global__ __launch_bounds__(256)
void gemm_l0(const float* __restrict__ A, const float* __restrict__ W,
             const float* __restrict__ bias, u16* __restrict__ Y) {
    __shared__ float As[16][68];   // [k][row]
    __shared__ float Bs[16][68];   // [k][col]
    const int tid = threadIdx.x;
    const int tx = tid & 15, ty = tid >> 4;
    const int brow = blockIdx.y * 64, bcol = blockIdx.x * 64;
    float acc[4][4] = {};
    for (int k0 = 0; k0 < I_DIM; k0 += 16) {
        {
            const int r = tid >> 2, c4 = (tid & 3) << 2;
            float4 v = *(const float4*)(A + (size_t)(brow + r) * I_DIM + k0 + c4);
            As[c4 + 0][r] = v.x; As[c4 + 1][r] = v.y;
            As[c4 + 2][r] = v.z; As[c4 + 3][r] = v.w;
        }
        {
            const int kr = tid >> 4, c4 = (tid & 15) << 2;
            *(float4*)(&Bs[kr][c4]) =
                *(const float4*)(W + (size_t)(k0 + kr) * H_DIM + bcol + c4);
        }
        __syncthreads();
        #pragma unroll
        for (int kk = 0; kk < 16; ++kk) {
            float4 av = *(const float4*)(&As[kk][ty << 2]);
            float4 bv = *(const float4*)(&Bs[kk][tx << 2]);
            float a_[4] = {av.x, av.y, av.z, av.w};
            float b_[4] = {bv.x, bv.y, bv.z, bv.w};
            #pragma unroll
            for (int i = 0; i < 4; ++i)
                #pragma unroll
                for (int j = 0; j < 4; ++j)
                    acc[i][j] = fmaf(a_[i], b_[j], acc[i][j]);
        }
        __syncthreads();
    }
    float4 bv = *(const float4*)(bias + bcol + (tx << 2));
    float bb[4] = {bv.x, bv.y, bv.z, bv.w};
    #pragma unroll
    for (int i = 0; i < 4; ++i) {
        ushort4 o;
        o.x = f2h(acc[i][0] + bb[0]); o.y = f2h(acc[i][1] + bb[1]);
        o.z = f2h(acc[i][2] + bb[2]); o.w = f2h(acc[i][3] + bb[3]);
        *(ushort4*)(Y + (size_t)(brow + (ty << 2) + i) * H_DIM + bcol + (tx << 2)) = o;
    }
}

// ---------------- layers 1..5: in-place full-row GEMM on act (fp16), K=H=256
// Block owns rows [brow, brow+64) x all 256 cols. Stages its A rows to LDS first,
// so overwriting them at the end is safe (blocks own disjoint rows).
__global__ __launch_bounds__(256)
void gemm_fullrow(u16* __restrict__ act, const float* __restrict__ W,
                  const float* __restrict__ bias) {
    __shared__ u16 As[64][264];   // fp16 bits, padded stride (528 B = 33*16)
    __shared__ u16 Ws[32][264];   // W k-chunk as fp16
    const int tid = threadIdx.x;
    const int tx = tid & 15;      // col group: cols [tx*16, tx*16+16)
    const int ty = tid >> 4;      // row group: rows [ty*4, ty*4+4)
    const size_t brow = (size_t)blockIdx.x * 64;

    // stage A tile: 64 rows x 256 fp16, 16B per thread per iter
    #pragma unroll
    for (int i = 0; i < 8; ++i) {
        int id = tid + i * 256;          // 0..2047 chunks of 8 halves
        int r  = id >> 5;                // 32 chunks per row
        int c8 = (id & 31) << 3;
        *(uint4*)(&As[r][c8]) = *(const uint4*)(act + (brow + r) * H_DIM + c8);
    }

    float acc[4][16] = {};
    for (int k0 = 0; k0 < H_DIM; k0 += 32) {
        __syncthreads();   // As ready (first iter) / prev Ws consumed
        // stage W chunk rows [k0,k0+32) as fp16
        #pragma unroll
        for (int i = 0; i < 8; ++i) {
            int id = tid + i * 256;      // 0..2047 quads
            int r  = id >> 6;            // 64 quads per row
            int q  = (id & 63) << 2;
            float4 v = *(const float4*)(W + (size_t)(k0 + r) * H_DIM + q);
            ushort4 o;
            o.x = f2h(v.x); o.y = f2h(v.y); o.z = f2h(v.z); o.w = f2h(v.w);
            *(ushort4*)(&Ws[r][q]) = o;
        }
        __syncthreads();
        #pragma unroll 4
        for (int kk = 0; kk < 32; kk += 4) {
            ushort4 a4[4];
            #pragma unroll
            for (int i = 0; i < 4; ++i)
                a4[i] = *(const ushort4*)(&As[ty * 4 + i][k0 + kk]);   // FIXED: k0 offset
            #pragma unroll
            for (int k = 0; k < 4; ++k) {
                uint4 w0 = *(const uint4*)(&Ws[kk + k][tx * 16]);
                uint4 w1 = *(const uint4*)(&Ws[kk + k][tx * 16 + 8]);
                float w[16];
                w[0]  = h2f((u16)(w0.x & 0xFFFF)); w[1]  = h2f((u16)(w0.x >> 16));
                w[2]  = h2f((u16)(w0.y & 0xFFFF)); w[3]  = h2f((u16)(w0.y >> 16));
                w[4]  = h2f((u16)(w0.z & 0xFFFF)); w[5]  = h2f((u16)(w0.z >> 16));
                w[6]  = h2f((u16)(w0.w & 0xFFFF)); w[7]  = h2f((u16)(w0.w >> 16));
                w[8]  = h2f((u16)(w1.x & 0xFFFF)); w[9]  = h2f((u16)(w1.x >> 16));
                w[10] = h2f((u16)(w1.y & 0xFFFF)); w[11] = h2f((u16)(w1.y >> 16));
                w[12] = h2f((u16)(w1.z & 0xFFFF)); w[13] = h2f((u16)(w1.z >> 16));
                w[14] = h2f((u16)(w1.w & 0xFFFF)); w[15] = h2f((u16)(w1.w >> 16));
                float a_[4];
                a_[0] = h2f(k == 0 ? a4[0].x : k == 1 ? a4[0].y : k == 2 ? a4[0].z : a4[0].w);
                a_[1] = h2f(k == 0 ? a4[1].x : k == 1 ? a4[1].y : k == 2 ? a4[1].z : a4[1].w);
                a_[2] = h2f(k == 0 ? a4[2].x : k == 1 ? a4[2].y : k == 2 ? a4[2].z : a4[2].w);
                a_[3] = h2f(k == 0 ? a4[3].x : k == 1 ? a4[3].y : k == 2 ? a4[3].z : a4[3].w);
                #pragma unroll
                for (int c = 0; c < 16; ++c)
                    #pragma unroll
                    for (int i = 0; i < 4; ++i)
                        acc[i][c] = fmaf(a_[i], w[c], acc[i][c]);
            }
        }
    }
    // bias + store (in-place over our own rows; all our reads were staged)
    float bb[16];
    #pragma unroll
    for (int c4 = 0; c4 < 16; c4 += 4) {
        float4 bv = *(const float4*)(bias + tx * 16 + c4);
        bb[c4] = bv.x; bb[c4 + 1] = bv.y; bb[c4 + 2] = bv.z; bb[c4 + 3] = bv.w;
    }
    #pragma unroll
    for (int i = 0; i < 4; ++i) {
        u32 ov[8];
        #pragma unroll
        for (int c = 0; c < 8; ++c) {
            u16 lo = f2h(acc[i][2 * c]     + bb[2 * c]);
            u16 hi = f2h(acc[i][2 * c + 1] + bb[2 * c + 1]);
            ov[c] = (u32)lo | ((u32)hi << 16);
        }
        u16* dst = act + (brow + ty * 4 + i) * H_DIM + tx * 16;
        *(uint4*)(dst)     = uint4{ov[0], ov[1], ov[2], ov[3]};
        *(uint4*)(dst + 8) = uint4{ov[4], ov[5], ov[6], ov[7]};
    }
}

// ---------------- BN stats: per-channel partial sum/sumsq, deterministic 2-stage
__global__ __launch_bounds__(256)
void bn_stats(const u16* __restrict__ Y, float* __restrict__ psum,
              float* __restrict__ psumsq) {
    const int c = threadIdx.x;
    const size_t row0 = (size_t)blockIdx.x * 512;
    float s = 0.f, q = 0.f;
    #pragma unroll 16
    for (int r = 0; r < 512; ++r) {
        float v = h2f(Y[(row0 + r) * H_DIM + c]);
        s += v; q = fmaf(v, v, q);
    }
    psum[blockIdx.x * H_DIM + c] = s;
    psumsq[blockIdx.x * H_DIM + c] = q;
}

__global__ void bn_finalize(const float* __restrict__ psum, const float* __restrict__ psumsq,
                            const float* __restrict__ gamma, const float* __restrict__ beta,
                            float* __restrict__ af, float* __restrict__ shf) {
    const int c = threadIdx.x;
    float s = 0.f, q = 0.f;
    for (int i = 0; i < 256; ++i) {
        s += psum[i * H_DIM + c];
        q += psumsq[i * H_DIM + c];
    }
    const float inv = 1.0f / (float)M_DIM;
    float m = s * inv;
    float v = q * inv - m * m;
    float a = gamma[c] * rsqrtf(v + 1e-5f);
    af[c] = a;
    shf[c] = fmaf(-m, a, beta[c]);
}

// ---------------- in-place scan: h_t = relu(a*y_t + sh + u*h_{t-1})
// src/dst alias act. Safe: the store to row R depends (via the h chain) on the
// load of row R issued PF iterations earlier, so no reordering can swap them;
// lanes touch disjoint columns.
__global__ __launch_bounds__(64)
void indrnn_scan(const u16* __restrict__ src, u16* __restrict__ dst,
                 const float* __restrict__ af, const float* __restrict__ shf,
                 const float* __restrict__ u) {
    const int off = blockIdx.x * 64 + threadIdx.x;   // 0..16383
    const int c = off & (H_DIM - 1);
    const float a = af[c], sh = shf[c], uu = u[c];
    constexpr int PF = 64;
    float buf[PF];
    #pragma unroll
    for (int i = 0; i < PF; ++i) buf[i] = h2f(src[(size_t)i * S_DIM + off]);
    float h = 0.f;
    for (int t = 0; t < T_DIM - PF; t += PF) {
        #pragma unroll
        for (int k = 0; k < PF; ++k) {
            float y = buf[k];
            buf[k] = h2f(src[(size_t)(t + PF + k) * S_DIM + off]);
            h = fmaxf(fmaf(uu, h, fmaf(a, y, sh)), 0.f);
            dst[(size_t)(t + k) * S_DIM + off] = f2h(h);
        }
    }
    #pragma unroll
    for (int k = 0; k < PF; ++k) {
        float y = buf[k];
        h = fmaxf(fmaf(uu, h, fmaf(a, y, sh)), 0.f);
        dst[(size_t)(T_DIM - PF + k) * S_DIM + off] = f2h(h);
    }
}

// ---------------- classifier: out[B,C] = h_last[B,H] @ Wc[H,C] + bc (f32 out)
__global__ __launch_bounds__(128)
void classifier(const u16* __restrict__ Hlast, const float* __restrict__ Wc,
                const float* __restrict__ bc, float* __restrict__ out) {
    __shared__ float hrow[H_DIM];
    const int b = blockIdx.x, tid = threadIdx.x;
    hrow[tid]       = h2f(Hlast[(size_t)b * H_DIM + tid]);
    hrow[tid + 128] = h2f(Hlast[(size_t)b * H_DIM + tid + 128]);
    __syncthreads();
    if (tid < C_DIM) {
        float s = bc[tid];
        #pragma unroll 8
        for (int hh = 0; hh < H_DIM; ++hh)
            s = fmaf(hrow[hh], Wc[(size_t)hh * C_DIM + tid], s);
        out[(size_t)b * C_DIM + tid] = s;
    }
}

extern "C" void kernel_launch(void* const* d_in, const int* in_sizes, int n_in,
                              void* d_out, int out_size, void* d_ws, size_t ws_size,
                              hipStream_t stream) {
    const float* x     = (const float*)d_in[0];
    const float* W0    = (const float*)d_in[1];
    const float* b0    = (const float*)d_in[2];
    const float* Wl    = (const float*)d_in[3];
    const float* bl    = (const float*)d_in[4];
    const float* u     = (const float*)d_in[5];
    const float* gamma = (const float*)d_in[6];
    const float* beta  = (const float*)d_in[7];
    const float* Wc    = (const float*)d_in[8];
    const float* bc    = (const float*)d_in[9];
    float* out = (float*)d_out;

    const size_t actElems = (size_t)M_DIM * H_DIM;            // 33.55M fp16
    u16*   act    = (u16*)d_ws;                               // 67.11 MB
    float* psum   = (float*)((char*)d_ws + actElems * sizeof(u16));
    float* psumsq = psum + 256 * H_DIM;                       // 256 KB each
    float* af     = psumsq + 256 * H_DIM;
    float* shf    = af + H_DIM;
    // total ws use: ~64.6 MiB

    for (int l = 0; l < L_DIM; ++l) {
        if (l == 0) {
            gemm_l0<<<dim3(H_DIM / 64, M_DIM / 64), 256, 0, stream>>>(x, W0, b0, act);
        } else {
            gemm_fullrow<<<M_DIM / 64, 256, 0, stream>>>(
                act, Wl + (size_t)(l - 1) * H_DIM * H_DIM, bl + (size_t)(l - 1) * H_DIM);
        }
        bn_stats<<<256, 256, 0, stream>>>(act, psum, psumsq);
        bn_finalize<<<1, 256, 0, stream>>>(psum, psumsq, gamma + l * H_DIM,
                                           beta + l * H_DIM, af, shf);
        indrnn_scan<<<S_DIM / 64, 64, 0, stream>>>(act, act, af, shf, u + l * H_DIM);
    }
    classifier<<<B_DIM, 128, 0, stream>>>(act + (size_t)(T_DIM - 1) * S_DIM, Wc, bc, out);
}

// Round 4
// 1244.149 us; speedup vs baseline: 2.6223x; 2.6223x over previous
//
#include <hip/hip_runtime.h>
#include <hip/hip_fp16.h>

#define T_DIM 2048
#define B_DIM 64
#define I_DIM 128
#define H_DIM 256
#define L_DIM 6
#define C_DIM 100
#define M_DIM (T_DIM * B_DIM)   // 131072 rows
#define S_DIM (B_DIM * H_DIM)   // 16384 chains

typedef unsigned short u16;
typedef unsigned int   u32;
typedef _Float16 f16;
typedef f16   f16x8 __attribute__((ext_vector_type(8)));
typedef float f32x4 __attribute__((ext_vector_type(4)));

__device__ __forceinline__ float h2f(u16 u) { return __half2float(__ushort_as_half(u)); }
__device__ __forceinline__ u16   f2h(float f) { return __half_as_ushort(__float2half(f)); }
__device__ __forceinline__ u32   packh(float a, float b) {
    return (u32)f2h(a) | ((u32)f2h(b) << 16);
}

// ---------------- weight transpose+convert: W[K][256] f32 -> Wtc[K/32][256][32] f16
__global__ void wt_convert(const float* __restrict__ W, u16* __restrict__ Wtc, int K) {
    int idx = blockIdx.x * 256 + threadIdx.x;   // col fastest -> coalesced reads
    if (idx >= K * 256) return;
    int col = idx & 255, k = idx >> 8;
    Wtc[(size_t)(k >> 5) * 8192 + col * 32 + (k & 31)] = f2h(W[idx]);
}

// ---------------- MFMA GEMM: Y[M,256] = A[M,K] @ W[K,256] + bias, fp16 out, in-place-safe
// Block: 64 rows x all 256 cols, 4 waves (wave w -> cols [w*64, w*64+64)).
// A staged to padded LDS up front (so in-place overwrite is safe);
// W chunks [256][32] f16 reg-double-buffered through LDS.
template<int K, bool AF32>
__global__ __launch_bounds__(256)
void gemm_mfma(const void* Asrc, const u16* __restrict__ Wtc,
               const float* __restrict__ bias, u16* Yout) {
    constexpr int NK = K / 32;
    constexpr int AROWB = AF32 ? 272 : 528;   // padded LDS row bytes (17/33 x16B -> conflict-free)
    __shared__ char Alds[64 * AROWB];
    __shared__ char Wlds[256 * 80];           // 80B rows (5 x16B slots)
    const int tid  = threadIdx.x;
    const int lane = tid & 63;
    const int wave = tid >> 6;
    const size_t brow = (size_t)blockIdx.x * 64;

    // ---- stage A (src rows are 512B in both cases: K*4B or K*2B)
    {
        const char* A = (const char*)Asrc + brow * (AF32 ? K * 4 : K * 2);
        #pragma unroll
        for (int i = 0; i < 8; ++i) {
            int off = i * 4096 + tid * 16;    // linear byte offset, 32KB total
            int row = off >> 9;
            int inb = off & 511;
            if (AF32) {
                float4 v = *(const float4*)(A + off);
                uint2 o = { packh(v.x, v.y), packh(v.z, v.w) };
                *(uint2*)(Alds + row * AROWB + (inb >> 1)) = o;
            } else {
                *(uint4*)(Alds + row * AROWB + inb) = *(const uint4*)(A + off);
            }
        }
    }

    // ---- preload W chunk 0 into regs
    uint4 wreg[4];
    {
        const u16* src = Wtc + (size_t)tid * 32;
        #pragma unroll
        for (int q = 0; q < 4; ++q) wreg[q] = *(const uint4*)(src + q * 8);
    }

    f32x4 acc[4][4];
    #pragma unroll
    for (int m = 0; m < 4; ++m)
        #pragma unroll
        for (int n = 0; n < 4; ++n)
            acc[m][n] = f32x4{0.f, 0.f, 0.f, 0.f};

    for (int kc = 0; kc < NK; ++kc) {
        __syncthreads();   // Wlds free (prev reads done); also A-writes fence on first iter
        // ds_write current chunk (regs loaded a full iteration ago)
        {
            char* dst = Wlds + tid * 80;
            #pragma unroll
            for (int q = 0; q < 4; ++q) *(uint4*)(dst + q * 16) = wreg[q];
        }
        __syncthreads();   // Wlds ready
        // issue next chunk's global loads (latency hidden under MFMA below)
        if (kc + 1 < NK) {
            const u16* src = Wtc + (size_t)(kc + 1) * 8192 + (size_t)tid * 32;
            #pragma unroll
            for (int q = 0; q < 4; ++q) wreg[q] = *(const uint4*)(src + q * 8);
        }
        // fragments + MFMA
        f16x8 afr[4], bfr[4];
        #pragma unroll
        for (int m = 0; m < 4; ++m) {
            int row = m * 16 + (lane & 15);
            afr[m] = *(const f16x8*)(Alds + row * AROWB + (kc * 32 + ((lane >> 4) << 3)) * 2);
        }
        #pragma unroll
        for (int n = 0; n < 4; ++n) {
            int col = wave * 64 + n * 16 + (lane & 15);
            bfr[n] = *(const f16x8*)(Wlds + col * 80 + ((lane >> 4) << 4));
        }
        #pragma unroll
        for (int m = 0; m < 4; ++m)
            #pragma unroll
            for (int n = 0; n < 4; ++n)
                acc[m][n] = __builtin_amdgcn_mfma_f32_16x16x32_f16(afr[m], bfr[n], acc[m][n], 0, 0, 0);
    }

    // ---- epilogue: bias + fp16 store (rows owned exclusively by this block)
    #pragma unroll
    for (int n = 0; n < 4; ++n) {
        int gcol = wave * 64 + n * 16 + (lane & 15);
        float bv = bias[gcol];
        #pragma unroll
        for (int m = 0; m < 4; ++m) {
            #pragma unroll
            for (int r = 0; r < 4; ++r) {
                size_t grow = brow + m * 16 + ((lane >> 4) << 2) + r;
                Yout[grow * H_DIM + gcol] = f2h(acc[m][n][r] + bv);
            }
        }
    }
}

// ---------------- BN stats: vectorized, deterministic 2-stage (256 partial blocks)
__global__ __launch_bounds__(256)
void bn_stats(const u16* __restrict__ Y, float* __restrict__ psum,
              float* __restrict__ psumsq) {
    __shared__ float Ls[8][256];
    __shared__ float Lq[8][256];
    const int tid = threadIdx.x;
    const int oc = tid & 31, sub = tid >> 5;
    const size_t row0 = (size_t)blockIdx.x * 512 + sub * 64;
    float s[8] = {}, q[8] = {};
    for (int r = 0; r < 64; ++r) {
        uint4 v = *(const uint4*)(Y + (row0 + r) * H_DIM + oc * 8);
        u32 w[4] = {v.x, v.y, v.z, v.w};
        #pragma unroll
        for (int j = 0; j < 4; ++j) {
            float f0 = h2f((u16)(w[j] & 0xFFFF));
            float f1 = h2f((u16)(w[j] >> 16));
            s[2 * j] += f0;     q[2 * j]     = fmaf(f0, f0, q[2 * j]);
            s[2 * j + 1] += f1; q[2 * j + 1] = fmaf(f1, f1, q[2 * j + 1]);
        }
    }
    #pragma unroll
    for (int j = 0; j < 8; ++j) { Ls[sub][oc * 8 + j] = s[j]; Lq[sub][oc * 8 + j] = q[j]; }
    __syncthreads();
    float ss = 0.f, qq = 0.f;
    #pragma unroll
    for (int i = 0; i < 8; ++i) { ss += Ls[i][tid]; qq += Lq[i][tid]; }
    psum[blockIdx.x * H_DIM + tid] = ss;
    psumsq[blockIdx.x * H_DIM + tid] = qq;
}

__global__ void bn_finalize(const float* __restrict__ psum, const float* __restrict__ psumsq,
                            const float* __restrict__ gamma, const float* __restrict__ beta,
                            float* __restrict__ af, float* __restrict__ shf) {
    const int c = threadIdx.x;
    float s = 0.f, q = 0.f;
    for (int i = 0; i < 256; ++i) {
        s += psum[i * H_DIM + c];
        q += psumsq[i * H_DIM + c];
    }
    const float inv = 1.0f / (float)M_DIM;
    float m = s * inv;
    float v = q * inv - m * m;
    float a = gamma[c] * rsqrtf(v + 1e-5f);
    af[c] = a;
    shf[c] = fmaf(-m, a, beta[c]);
}

// ---------------- scan: 2 channels per lane, raw-bits prefetch (convert at use)
// h_t = relu(a*y_t + sh + u*h_{t-1}); in-place safe (store of row r data-depends
// on the load of row r via the h chain).
__global__ __launch_bounds__(64)
void indrnn_scan2(const u32* __restrict__ src, u32* __restrict__ dst,
                  const float* __restrict__ af, const float* __restrict__ shf,
                  const float* __restrict__ uw) {
    const int p = blockIdx.x * 64 + threadIdx.x;   // 0..8191 channel-pairs
    const int c0 = (p * 2) & 255;
    const float a0 = af[c0],  a1 = af[c0 + 1];
    const float s0 = shf[c0], s1 = shf[c0 + 1];
    const float u0 = uw[c0],  u1 = uw[c0 + 1];
    constexpr int PF = 32;
    u32 buf[PF];
    #pragma unroll
    for (int i = 0; i < PF; ++i) buf[i] = src[(size_t)i * (S_DIM / 2) + p];
    float h0 = 0.f, h1 = 0.f;
    for (int t = 0; t < T_DIM - PF; t += PF) {
        #pragma unroll
        for (int k = 0; k < PF; ++k) {
            u32 w = buf[k];
            buf[k] = src[(size_t)(t + PF + k) * (S_DIM / 2) + p];
            float y0 = h2f((u16)(w & 0xFFFF));
            float y1 = h2f((u16)(w >> 16));
            h0 = fmaxf(fmaf(u0, h0, fmaf(a0, y0, s0)), 0.f);
            h1 = fmaxf(fmaf(u1, h1, fmaf(a1, y1, s1)), 0.f);
            dst[(size_t)(t + k) * (S_DIM / 2) + p] = packh(h0, h1);
        }
    }
    #pragma unroll
    for (int k = 0; k < PF; ++k) {
        u32 w = buf[k];
        float y0 = h2f((u16)(w & 0xFFFF));
        float y1 = h2f((u16)(w >> 16));
        h0 = fmaxf(fmaf(u0, h0, fmaf(a0, y0, s0)), 0.f);
        h1 = fmaxf(fmaf(u1, h1, fmaf(a1, y1, s1)), 0.f);
        dst[(size_t)(T_DIM - PF + k) * (S_DIM / 2) + p] = packh(h0, h1);
    }
}

// ---------------- classifier: out[B,C] = h_last[B,H] @ Wc[H,C] + bc (f32 out)
__global__ __launch_bounds__(128)
void classifier(const u16* __restrict__ Hlast, const float* __restrict__ Wc,
                const float* __restrict__ bc, float* __restrict__ out) {
    __shared__ float hrow[H_DIM];
    const int b = blockIdx.x, tid = threadIdx.x;
    hrow[tid]       = h2f(Hlast[(size_t)b * H_DIM + tid]);
    hrow[tid + 128] = h2f(Hlast[(size_t)b * H_DIM + tid + 128]);
    __syncthreads();
    if (tid < C_DIM) {
        float s = bc[tid];
        #pragma unroll 8
        for (int hh = 0; hh < H_DIM; ++hh)
            s = fmaf(hrow[hh], Wc[(size_t)hh * C_DIM + tid], s);
        out[(size_t)b * C_DIM + tid] = s;
    }
}

extern "C" void kernel_launch(void* const* d_in, const int* in_sizes, int n_in,
                              void* d_out, int out_size, void* d_ws, size_t ws_size,
                              hipStream_t stream) {
    const float* x     = (const float*)d_in[0];
    const float* W0    = (const float*)d_in[1];
    const float* b0    = (const float*)d_in[2];
    const float* Wl    = (const float*)d_in[3];
    const float* bl    = (const float*)d_in[4];
    const float* u     = (const float*)d_in[5];
    const float* gamma = (const float*)d_in[6];
    const float* beta  = (const float*)d_in[7];
    const float* Wc    = (const float*)d_in[8];
    const float* bc    = (const float*)d_in[9];
    float* out = (float*)d_out;

    // workspace layout (~68.4 MB)
    char* ws = (char*)d_ws;
    u16* act = (u16*)ws;                 ws += (size_t)M_DIM * H_DIM * 2;  // 64 MiB
    u16* Wt0 = (u16*)ws;                 ws += (size_t)4 * 8192 * 2;       // 64 KiB
    u16* Wtl = (u16*)ws;                 ws += (size_t)5 * 8 * 8192 * 2;   // 640 KiB
    float* psum   = (float*)ws;          ws += 256 * H_DIM * 4;
    float* psumsq = (float*)ws;          ws += 256 * H_DIM * 4;
    float* af     = (float*)ws;          ws += H_DIM * 4;
    float* shf    = (float*)ws;          ws += H_DIM * 4;

    // one-time weight transpose/convert
    wt_convert<<<I_DIM, 256, 0, stream>>>(W0, Wt0, I_DIM);
    for (int l = 0; l < 5; ++l)
        wt_convert<<<H_DIM, 256, 0, stream>>>(Wl + (size_t)l * H_DIM * H_DIM,
                                              Wtl + (size_t)l * 8 * 8192, H_DIM);

    for (int l = 0; l < L_DIM; ++l) {
        if (l == 0) {
            gemm_mfma<I_DIM, true><<<M_DIM / 64, 256, 0, stream>>>(x, Wt0, b0, act);
        } else {
            gemm_mfma<H_DIM, false><<<M_DIM / 64, 256, 0, stream>>>(
                act, Wtl + (size_t)(l - 1) * 8 * 8192, bl + (size_t)(l - 1) * H_DIM, act);
        }
        bn_stats<<<256, 256, 0, stream>>>(act, psum, psumsq);
        bn_finalize<<<1, 256, 0, stream>>>(psum, psumsq, gamma + l * H_DIM,
                                           beta + l * H_DIM, af, shf);
        indrnn_scan2<<<S_DIM / 128, 64, 0, stream>>>((const u32*)act, (u32*)act,
                                                     af, shf, u + l * H_DIM);
    }
    classifier<<<B_DIM, 128, 0, stream>>>(act + (size_t)(T_DIM - 1) * S_DIM, Wc, bc, out);
}

// Round 6
// 709.786 us; speedup vs baseline: 4.5965x; 1.7529x over previous
//
#include <hip/hip_runtime.h>
#include <hip/hip_fp16.h>

#define T_DIM 2048
#define B_DIM 64
#define I_DIM 128
#define H_DIM 256
#define L_DIM 6
#define C_DIM 100
#define M_DIM (T_DIM * B_DIM)   // 131072 rows
#define S_DIM (B_DIM * H_DIM)   // 16384 chains

typedef unsigned short u16;
typedef unsigned int   u32;
typedef _Float16 f16;
typedef f16   f16x8 __attribute__((ext_vector_type(8)));
typedef float f32x4 __attribute__((ext_vector_type(4)));

__device__ __forceinline__ float h2f(u16 u) { return __half2float(__ushort_as_half(u)); }
__device__ __forceinline__ u16   f2h(float f) { return __half_as_ushort(__float2half(f)); }
__device__ __forceinline__ u32   packh(float a, float b) {
    return (u32)f2h(a) | ((u32)f2h(b) << 16);
}

// ---------------- weight repack (all layers, one dispatch)
// chunk (w, kc, n, lane) -> f16[8] = W[k = kc*32 + (lane>>4)*8 + j][col = w*64 + n + 4*(lane&15)]
// flat chunk index: ((w*NK + kc)*4 + n)*64 + lane ; 16B per chunk.
__global__ __launch_bounds__(256)
void wt_convert_all(const float* __restrict__ W0, const float* __restrict__ Wl,
                    u16* __restrict__ Wt0, u16* __restrict__ Wtl) {
    int id = blockIdx.x * 256 + threadIdx.x;
    const float* W; u16* outp; int NK, lg, chunk;
    if (id < 4096) { W = W0; outp = Wt0; NK = 4; lg = 2; chunk = id; }
    else {
        int r = id - 4096;
        int l = r >> 13;                 // 8192 chunks per layer
        if (l >= 5) return;
        chunk = r & 8191;
        W = Wl + (size_t)l * H_DIM * H_DIM;
        outp = Wtl + (size_t)l * 65536;
        NK = 8; lg = 3;
    }
    int lane = chunk & 63;
    int rest = chunk >> 6;
    int n  = rest & 3; rest >>= 2;
    int kc = rest & (NK - 1);
    int w  = rest >> lg;
    int col = w * 64 + n + 4 * (lane & 15);
    int kb  = kc * 32 + (lane >> 4) * 8;
    u32 o[4];
    #pragma unroll
    for (int j = 0; j < 4; ++j)
        o[j] = packh(W[(size_t)(kb + 2 * j) * H_DIM + col],
                     W[(size_t)(kb + 2 * j + 1) * H_DIM + col]);
    *(uint4*)(outp + (size_t)chunk * 8) = uint4{o[0], o[1], o[2], o[3]};
}

// ---------------- MFMA GEMM, W-in-registers, fused bias + BN partial stats (f32).
// Block: 64 rows x 256 cols, 4 waves (wave w -> phys cols [w*64, w*64+64)).
// A staged once to LDS (in-place safe); K-loop has NO barriers.
template<int K, bool AF32>
__global__ __launch_bounds__(256, 2)
void gemm_mfma(const void* Asrc, const u16* __restrict__ Wtc,
               const float* __restrict__ bias, u16* Yout, float2* __restrict__ psum) {
    constexpr int NK = K / 32;
    constexpr int AROWB = AF32 ? 272 : 528;   // padded LDS row bytes
    __shared__ char Alds[64 * AROWB];
    const int tid  = threadIdx.x;
    const int lane = tid & 63;
    const int wave = tid >> 6;
    const int c    = lane & 15;
    const int g    = lane >> 4;
    const size_t brow = (size_t)blockIdx.x * 64;

    // ---- W panel into VGPRs (coalesced 16B/lane chunks; latency hides under staging)
    f16x8 wreg[NK][4];
    {
        const u16* base = Wtc + ((size_t)wave * NK * 4 * 64 + lane) * 8;
        #pragma unroll
        for (int kc = 0; kc < NK; ++kc)
            #pragma unroll
            for (int n = 0; n < 4; ++n)
                wreg[kc][n] = *(const f16x8*)(base + (size_t)(kc * 4 + n) * 64 * 8);
    }

    // ---- stage A (rows are 512B in both cases: K*4B or K*2B)
    {
        const char* A = (const char*)Asrc + brow * 512;
        #pragma unroll
        for (int i = 0; i < 8; ++i) {
            int off = i * 4096 + tid * 16;
            int row = off >> 9, inb = off & 511;
            if (AF32) {
                float4 v = *(const float4*)(A + off);
                uint2 o = { packh(v.x, v.y), packh(v.z, v.w) };
                *(uint2*)(Alds + row * AROWB + (inb >> 1)) = o;
            } else {
                *(uint4*)(Alds + row * AROWB + inb) = *(const uint4*)(A + off);
            }
        }
    }
    __syncthreads();

    f32x4 acc[4][4];
    #pragma unroll
    for (int m = 0; m < 4; ++m)
        #pragma unroll
        for (int n = 0; n < 4; ++n)
            acc[m][n] = f32x4{0.f, 0.f, 0.f, 0.f};

    #pragma unroll
    for (int kc = 0; kc < NK; ++kc) {
        f16x8 afr[4];
        #pragma unroll
        for (int m = 0; m < 4; ++m) {
            int row = m * 16 + c;
            afr[m] = *(const f16x8*)(Alds + row * AROWB + kc * 64 + (g << 4));
        }
        #pragma unroll
        for (int m = 0; m < 4; ++m)
            #pragma unroll
            for (int n = 0; n < 4; ++n)
                acc[m][n] = __builtin_amdgcn_mfma_f32_16x16x32_f16(afr[m], wreg[kc][n], acc[m][n], 0, 0, 0);
    }

    // ---- epilogue: bias, coalesced ushort4 stores, per-column partial stats
    float4 bv = *(const float4*)(bias + wave * 64 + 4 * c);
    float bb[4] = {bv.x, bv.y, bv.z, bv.w};
    float s[4] = {}, q[4] = {};
    #pragma unroll
    for (int m = 0; m < 4; ++m) {
        #pragma unroll
        for (int r = 0; r < 4; ++r) {
            float y0 = acc[m][0][r] + bb[0];
            float y1 = acc[m][1][r] + bb[1];
            float y2 = acc[m][2][r] + bb[2];
            float y3 = acc[m][3][r] + bb[3];
            s[0] += y0; q[0] = fmaf(y0, y0, q[0]);
            s[1] += y1; q[1] = fmaf(y1, y1, q[1]);
            s[2] += y2; q[2] = fmaf(y2, y2, q[2]);
            s[3] += y3; q[3] = fmaf(y3, y3, q[3]);
            size_t grow = brow + m * 16 + g * 4 + r;
            ushort4 o = { f2h(y0), f2h(y1), f2h(y2), f2h(y3) };
            *(ushort4*)(Yout + grow * H_DIM + wave * 64 + 4 * c) = o;
        }
    }
    #pragma unroll
    for (int n = 0; n < 4; ++n) {
        s[n] += __shfl_xor(s[n], 16, 64); s[n] += __shfl_xor(s[n], 32, 64);
        q[n] += __shfl_xor(q[n], 16, 64); q[n] += __shfl_xor(q[n], 32, 64);
    }
    if (g == 0) {
        float2* dst = psum + (size_t)blockIdx.x * 256 + wave * 64 + 4 * c;
        #pragma unroll
        for (int n = 0; n < 4; ++n) dst[n] = float2{s[n], q[n]};
    }
}

// ---------------- BN partial reduce: 2048 block-partials -> 64 -> af/shf
__global__ __launch_bounds__(256)
void bn_reduce1(const float2* __restrict__ psum, float2* __restrict__ p2) {
    const int cch = threadIdx.x, blk = blockIdx.x;
    float s = 0.f, q = 0.f;
    for (int i = 0; i < 32; ++i) {
        float2 p = psum[(size_t)(blk * 32 + i) * 256 + cch];
        s += p.x; q += p.y;
    }
    p2[blk * 256 + cch] = float2{s, q};
}

__global__ void bn_finalize(const float2* __restrict__ p2,
                            const float* __restrict__ gamma, const float* __restrict__ beta,
                            float* __restrict__ af, float* __restrict__ shf) {
    const int cch = threadIdx.x;
    float s = 0.f, q = 0.f;
    for (int i = 0; i < 64; ++i) {
        float2 v = p2[i * 256 + cch];
        s += v.x; q += v.y;
    }
    const float inv = 1.0f / (float)M_DIM;
    float m = s * inv;
    float v = q * inv - m * m;
    float a = gamma[cch] * rsqrtf(v + 1e-5f);
    af[cch] = a;
    shf[cch] = fmaf(-m, a, beta[cch]);
}

// ---------------- scan: 1 chain/lane (256 waves), raw-bits PF=64 prefetch, in-place.
// Safe without restrict: compiler assumes alias so program order (load t+PF+k
// before store t+k) is preserved; the same-row load precedes its store by PF steps.
__global__ __launch_bounds__(64)
void indrnn_scan1(const u16* src, u16* dst,
                  const float* __restrict__ af, const float* __restrict__ shf,
                  const float* __restrict__ uw) {
    const int off = blockIdx.x * 64 + threadIdx.x;   // 0..16383
    const int cch = off & (H_DIM - 1);
    const float a = af[cch], sh = shf[cch], uu = uw[cch];
    constexpr int PF = 64;
    u32 buf[PF];
    #pragma unroll
    for (int i = 0; i < PF; ++i) buf[i] = src[(size_t)i * S_DIM + off];
    float h = 0.f;
    for (int t = 0; t < T_DIM - PF; t += PF) {
        #pragma unroll
        for (int k = 0; k < PF; ++k) {
            float y = h2f((u16)buf[k]);
            buf[k] = src[(size_t)(t + PF + k) * S_DIM + off];
            h = fmaxf(fmaf(uu, h, fmaf(a, y, sh)), 0.f);
            dst[(size_t)(t + k) * S_DIM + off] = f2h(h);
        }
    }
    #pragma unroll
    for (int k = 0; k < PF; ++k) {
        float y = h2f((u16)buf[k]);
        h = fmaxf(fmaf(uu, h, fmaf(a, y, sh)), 0.f);
        dst[(size_t)(T_DIM - PF + k) * S_DIM + off] = f2h(h);
    }
}

// ---------------- classifier: out[B,C] = h_last[B,H] @ Wc[H,C] + bc (f32 out)
__global__ __launch_bounds__(128)
void classifier(const u16* __restrict__ Hlast, const float* __restrict__ Wc,
                const float* __restrict__ bc, float* __restrict__ out) {
    __shared__ float hrow[H_DIM];
    const int b = blockIdx.x, tid = threadIdx.x;
    hrow[tid]       = h2f(Hlast[(size_t)b * H_DIM + tid]);
    hrow[tid + 128] = h2f(Hlast[(size_t)b * H_DIM + tid + 128]);
    __syncthreads();
    if (tid < C_DIM) {
        float s = bc[tid];
        #pragma unroll 8
        for (int hh = 0; hh < H_DIM; ++hh)
            s = fmaf(hrow[hh], Wc[(size_t)hh * C_DIM + tid], s);
        out[(size_t)b * C_DIM + tid] = s;
    }
}

extern "C" void kernel_launch(void* const* d_in, const int* in_sizes, int n_in,
                              void* d_out, int out_size, void* d_ws, size_t ws_size,
                              hipStream_t stream) {
    const float* x     = (const float*)d_in[0];
    const float* W0    = (const float*)d_in[1];
    const float* b0    = (const float*)d_in[2];
    const float* Wl    = (const float*)d_in[3];
    const float* bl    = (const float*)d_in[4];
    const float* u     = (const float*)d_in[5];
    const float* gamma = (const float*)d_in[6];
    const float* beta  = (const float*)d_in[7];
    const float* Wc    = (const float*)d_in[8];
    const float* bc    = (const float*)d_in[9];
    float* out = (float*)d_out;

    // workspace (~72 MB)
    char* ws = (char*)d_ws;
    u16* act = (u16*)ws;                 ws += (size_t)M_DIM * H_DIM * 2;   // 67.1 MB
    u16* Wt0 = (u16*)ws;                 ws += (size_t)32768 * 2;           // 64 KB
    u16* Wtl = (u16*)ws;                 ws += (size_t)5 * 65536 * 2;       // 640 KB
    float2* psum = (float2*)ws;          ws += (size_t)2048 * 256 * 8;      // 4 MB (f32 pairs)
    float2* p2 = (float2*)ws;            ws += (size_t)64 * 256 * 8;        // 128 KB
    float* af  = (float*)ws;             ws += H_DIM * 4;
    float* shf = (float*)ws;             ws += H_DIM * 4;

    wt_convert_all<<<176, 256, 0, stream>>>(W0, Wl, Wt0, Wtl);

    for (int l = 0; l < L_DIM; ++l) {
        if (l == 0) {
            gemm_mfma<I_DIM, true><<<M_DIM / 64, 256, 0, stream>>>(x, Wt0, b0, act, psum);
        } else {
            gemm_mfma<H_DIM, false><<<M_DIM / 64, 256, 0, stream>>>(
                act, Wtl + (size_t)(l - 1) * 65536, bl + (size_t)(l - 1) * H_DIM, act, psum);
        }
        bn_reduce1<<<64, 256, 0, stream>>>(psum, p2);
        bn_finalize<<<1, 256, 0, stream>>>(p2, gamma + l * H_DIM, beta + l * H_DIM, af, shf);
        indrnn_scan1<<<S_DIM / 64, 64, 0, stream>>>(act, act, af, shf, u + l * H_DIM);
    }
    classifier<<<B_DIM, 128, 0, stream>>>(act + (size_t)(T_DIM - 1) * S_DIM, Wc, bc, out);
}

// Round 7
// 467.831 us; speedup vs baseline: 6.9737x; 1.5172x over previous
//
#include <hip/hip_runtime.h>
#include <hip/hip_fp16.h>

#define T_DIM 2048
#define B_DIM 64
#define I_DIM 128
#define H_DIM 256
#define L_DIM 6
#define C_DIM 100
#define M_DIM (T_DIM * B_DIM)   // 131072 rows
#define S_DIM (B_DIM * H_DIM)   // 16384 chains
#define CHUNK 64
#define NC (T_DIM / CHUNK)      // 32 chunks

typedef unsigned short u16;
typedef unsigned int   u32;
typedef _Float16 f16;
typedef f16   f16x8 __attribute__((ext_vector_type(8)));
typedef float f32x4 __attribute__((ext_vector_type(4)));

__device__ __forceinline__ float h2f(u16 u) { return __half2float(__ushort_as_half(u)); }
__device__ __forceinline__ u16   f2h(float f) { return __half_as_ushort(__float2half(f)); }
__device__ __forceinline__ u32   packh(float a, float b) {
    return (u32)f2h(a) | ((u32)f2h(b) << 16);
}

// ---------------- weight repack (all layers, one dispatch)
__global__ __launch_bounds__(256)
void wt_convert_all(const float* __restrict__ W0, const float* __restrict__ Wl,
                    u16* __restrict__ Wt0, u16* __restrict__ Wtl) {
    int id = blockIdx.x * 256 + threadIdx.x;
    const float* W; u16* outp; int NK, lg, chunk;
    if (id < 4096) { W = W0; outp = Wt0; NK = 4; lg = 2; chunk = id; }
    else {
        int r = id - 4096;
        int l = r >> 13;
        if (l >= 5) return;
        chunk = r & 8191;
        W = Wl + (size_t)l * H_DIM * H_DIM;
        outp = Wtl + (size_t)l * 65536;
        NK = 8; lg = 3;
    }
    int lane = chunk & 63;
    int rest = chunk >> 6;
    int n  = rest & 3; rest >>= 2;
    int kc = rest & (NK - 1);
    int w  = rest >> lg;
    int col = w * 64 + n + 4 * (lane & 15);
    int kb  = kc * 32 + (lane >> 4) * 8;
    u32 o[4];
    #pragma unroll
    for (int j = 0; j < 4; ++j)
        o[j] = packh(W[(size_t)(kb + 2 * j) * H_DIM + col],
                     W[(size_t)(kb + 2 * j + 1) * H_DIM + col]);
    *(uint4*)(outp + (size_t)chunk * 8) = uint4{o[0], o[1], o[2], o[3]};
}

// ---------------- MFMA GEMM, W-in-registers, fused bias + BN partial stats (f32).
template<int K, bool AF32>
__global__ __launch_bounds__(256, 2)
void gemm_mfma(const void* Asrc, const u16* __restrict__ Wtc,
               const float* __restrict__ bias, u16* Yout, float2* __restrict__ psum) {
    constexpr int NK = K / 32;
    constexpr int AROWB = AF32 ? 272 : 528;
    __shared__ char Alds[64 * AROWB];
    const int tid  = threadIdx.x;
    const int lane = tid & 63;
    const int wave = tid >> 6;
    const int c    = lane & 15;
    const int g    = lane >> 4;
    const size_t brow = (size_t)blockIdx.x * 64;

    f16x8 wreg[NK][4];
    {
        const u16* base = Wtc + ((size_t)wave * NK * 4 * 64 + lane) * 8;
        #pragma unroll
        for (int kc = 0; kc < NK; ++kc)
            #pragma unroll
            for (int n = 0; n < 4; ++n)
                wreg[kc][n] = *(const f16x8*)(base + (size_t)(kc * 4 + n) * 64 * 8);
    }
    {
        const char* A = (const char*)Asrc + brow * 512;
        #pragma unroll
        for (int i = 0; i < 8; ++i) {
            int off = i * 4096 + tid * 16;
            int row = off >> 9, inb = off & 511;
            if (AF32) {
                float4 v = *(const float4*)(A + off);
                uint2 o = { packh(v.x, v.y), packh(v.z, v.w) };
                *(uint2*)(Alds + row * AROWB + (inb >> 1)) = o;
            } else {
                *(uint4*)(Alds + row * AROWB + inb) = *(const uint4*)(A + off);
            }
        }
    }
    __syncthreads();

    f32x4 acc[4][4];
    #pragma unroll
    for (int m = 0; m < 4; ++m)
        #pragma unroll
        for (int n = 0; n < 4; ++n)
            acc[m][n] = f32x4{0.f, 0.f, 0.f, 0.f};

    #pragma unroll
    for (int kc = 0; kc < NK; ++kc) {
        f16x8 afr[4];
        #pragma unroll
        for (int m = 0; m < 4; ++m) {
            int row = m * 16 + c;
            afr[m] = *(const f16x8*)(Alds + row * AROWB + kc * 64 + (g << 4));
        }
        #pragma unroll
        for (int m = 0; m < 4; ++m)
            #pragma unroll
            for (int n = 0; n < 4; ++n)
                acc[m][n] = __builtin_amdgcn_mfma_f32_16x16x32_f16(afr[m], wreg[kc][n], acc[m][n], 0, 0, 0);
    }

    float4 bv = *(const float4*)(bias + wave * 64 + 4 * c);
    float bb[4] = {bv.x, bv.y, bv.z, bv.w};
    float s[4] = {}, q[4] = {};
    #pragma unroll
    for (int m = 0; m < 4; ++m) {
        #pragma unroll
        for (int r = 0; r < 4; ++r) {
            float y0 = acc[m][0][r] + bb[0];
            float y1 = acc[m][1][r] + bb[1];
            float y2 = acc[m][2][r] + bb[2];
            float y3 = acc[m][3][r] + bb[3];
            s[0] += y0; q[0] = fmaf(y0, y0, q[0]);
            s[1] += y1; q[1] = fmaf(y1, y1, q[1]);
            s[2] += y2; q[2] = fmaf(y2, y2, q[2]);
            s[3] += y3; q[3] = fmaf(y3, y3, q[3]);
            size_t grow = brow + m * 16 + g * 4 + r;
            ushort4 o = { f2h(y0), f2h(y1), f2h(y2), f2h(y3) };
            *(ushort4*)(Yout + grow * H_DIM + wave * 64 + 4 * c) = o;
        }
    }
    #pragma unroll
    for (int n = 0; n < 4; ++n) {
        s[n] += __shfl_xor(s[n], 16, 64); s[n] += __shfl_xor(s[n], 32, 64);
        q[n] += __shfl_xor(q[n], 16, 64); q[n] += __shfl_xor(q[n], 32, 64);
    }
    if (g == 0) {
        float2* dst = psum + (size_t)blockIdx.x * 256 + wave * 64 + 4 * c;
        #pragma unroll
        for (int n = 0; n < 4; ++n) dst[n] = float2{s[n], q[n]};
    }
}

// ---------------- BN partial reduce: 2048 block-partials -> 64 -> af/shf
__global__ __launch_bounds__(256)
void bn_reduce1(const float2* __restrict__ psum, float2* __restrict__ p2) {
    const int cch = threadIdx.x, blk = blockIdx.x;
    float s = 0.f, q = 0.f;
    for (int i = 0; i < 32; ++i) {
        float2 p = psum[(size_t)(blk * 32 + i) * 256 + cch];
        s += p.x; q += p.y;
    }
    p2[blk * 256 + cch] = float2{s, q};
}

__global__ void bn_finalize(const float2* __restrict__ p2,
                            const float* __restrict__ gamma, const float* __restrict__ beta,
                            float* __restrict__ af, float* __restrict__ shf) {
    const int cch = threadIdx.x;
    float s = 0.f, q = 0.f;
    for (int i = 0; i < 64; ++i) {
        float2 v = p2[i * 256 + cch];
        s += v.x; q += v.y;
    }
    const float inv = 1.0f / (float)M_DIM;
    float m = s * inv;
    float v = q * inv - m * m;
    float a = gamma[cch] * rsqrtf(v + 1e-5f);
    af[cch] = a;
    shf[cch] = fmaf(-m, a, beta[cch]);
}

// ---------------- parallel scan via affine-max composition.
// step f(h) = max(u*h + yn, 0); class F(h)=max(a*h+b,c) closed under composition:
// (f∘F): a'=u*a, b'=u*b+yn, c'=max(u*c+yn, 0).
// K1: each lane composes one 64-step chunk of one chain -> (a,b,c).
__global__ __launch_bounds__(256)
void scan_compose(const u16* __restrict__ y, const float* __restrict__ af,
                  const float* __restrict__ shf, const float* __restrict__ uw,
                  float* __restrict__ ca, float* __restrict__ cb, float* __restrict__ cc) {
    const int lane  = threadIdx.x & 63;
    const int chain = blockIdx.x * 64 + lane;
    const int chunk = blockIdx.y * 4 + (threadIdx.x >> 6);
    const int cch   = chain & (H_DIM - 1);
    const float A = af[cch], SH = shf[cch], U = uw[cch];
    const size_t base = (size_t)chunk * CHUNK * S_DIM + chain;
    u16 buf[8];
    #pragma unroll
    for (int i = 0; i < 8; ++i) buf[i] = y[base + (size_t)i * S_DIM];
    float a = 1.f, b = 0.f, c = -1e30f;   // ~identity; c=-1e30 avoids 0*inf NaN, output-exact
    #pragma unroll 8
    for (int k = 0; k < CHUNK - 8; ++k) {
        float yv = h2f(buf[k & 7]);
        buf[k & 7] = y[base + (size_t)(k + 8) * S_DIM];
        float yn = fmaf(A, yv, SH);
        a *= U;
        b = fmaf(U, b, yn);
        c = fmaxf(fmaf(U, c, yn), 0.f);
    }
    #pragma unroll
    for (int k = CHUNK - 8; k < CHUNK; ++k) {
        float yv = h2f(buf[k & 7]);
        float yn = fmaf(A, yv, SH);
        a *= U;
        b = fmaf(U, b, yn);
        c = fmaxf(fmaf(U, c, yn), 0.f);
    }
    const size_t ci = (size_t)chunk * S_DIM + chain;
    ca[ci] = a; cb[ci] = b; cc[ci] = c;
}

// K2: serial prefix over the 32 chunk-composites per chain -> h_in per chunk.
__global__ __launch_bounds__(64)
void scan_prefix(const float* __restrict__ ca, const float* __restrict__ cb,
                 const float* __restrict__ cc, float* __restrict__ hin) {
    const int chain = blockIdx.x * 64 + threadIdx.x;
    float av[NC], bv[NC], cv[NC];
    #pragma unroll
    for (int i = 0; i < NC; ++i) {
        av[i] = ca[(size_t)i * S_DIM + chain];
        bv[i] = cb[(size_t)i * S_DIM + chain];
        cv[i] = cc[(size_t)i * S_DIM + chain];
    }
    float h = 0.f;
    #pragma unroll
    for (int i = 0; i < NC; ++i) {
        hin[(size_t)i * S_DIM + chain] = h;
        h = fmaxf(fmaf(av[i], h, bv[i]), cv[i]);
    }
}

// K3: replay each chunk from its exact h_in, write h over y in place.
__global__ __launch_bounds__(256)
void scan_apply(u16* y, const float* __restrict__ af, const float* __restrict__ shf,
                const float* __restrict__ uw, const float* __restrict__ hin) {
    const int lane  = threadIdx.x & 63;
    const int chain = blockIdx.x * 64 + lane;
    const int chunk = blockIdx.y * 4 + (threadIdx.x >> 6);
    const int cch   = chain & (H_DIM - 1);
    const float A = af[cch], SH = shf[cch], U = uw[cch];
    const size_t base = (size_t)chunk * CHUNK * S_DIM + chain;
    float h = hin[(size_t)chunk * S_DIM + chain];
    u16 buf[8];
    #pragma unroll
    for (int i = 0; i < 8; ++i) buf[i] = y[base + (size_t)i * S_DIM];
    #pragma unroll 8
    for (int k = 0; k < CHUNK - 8; ++k) {
        float yv = h2f(buf[k & 7]);
        buf[k & 7] = y[base + (size_t)(k + 8) * S_DIM];
        h = fmaxf(fmaf(U, h, fmaf(A, yv, SH)), 0.f);
        y[base + (size_t)k * S_DIM] = f2h(h);
    }
    #pragma unroll
    for (int k = CHUNK - 8; k < CHUNK; ++k) {
        float yv = h2f(buf[k & 7]);
        h = fmaxf(fmaf(U, h, fmaf(A, yv, SH)), 0.f);
        y[base + (size_t)k * S_DIM] = f2h(h);
    }
}

// ---------------- classifier: out[B,C] = h_last[B,H] @ Wc[H,C] + bc (f32 out)
__global__ __launch_bounds__(128)
void classifier(const u16* __restrict__ Hlast, const float* __restrict__ Wc,
                const float* __restrict__ bc, float* __restrict__ out) {
    __shared__ float hrow[H_DIM];
    const int b = blockIdx.x, tid = threadIdx.x;
    hrow[tid]       = h2f(Hlast[(size_t)b * H_DIM + tid]);
    hrow[tid + 128] = h2f(Hlast[(size_t)b * H_DIM + tid + 128]);
    __syncthreads();
    if (tid < C_DIM) {
        float s = bc[tid];
        #pragma unroll 8
        for (int hh = 0; hh < H_DIM; ++hh)
            s = fmaf(hrow[hh], Wc[(size_t)hh * C_DIM + tid], s);
        out[(size_t)b * C_DIM + tid] = s;
    }
}

extern "C" void kernel_launch(void* const* d_in, const int* in_sizes, int n_in,
                              void* d_out, int out_size, void* d_ws, size_t ws_size,
                              hipStream_t stream) {
    const float* x     = (const float*)d_in[0];
    const float* W0    = (const float*)d_in[1];
    const float* b0    = (const float*)d_in[2];
    const float* Wl    = (const float*)d_in[3];
    const float* bl    = (const float*)d_in[4];
    const float* u     = (const float*)d_in[5];
    const float* gamma = (const float*)d_in[6];
    const float* beta  = (const float*)d_in[7];
    const float* Wc    = (const float*)d_in[8];
    const float* bc    = (const float*)d_in[9];
    float* out = (float*)d_out;

    // workspace (~76 MB). Union region: psum (4 MB, dead after bn_reduce1)
    // overlaid by ca/cb/cc+hin (8 MB, live finalize->scan_apply). Next layer's
    // GEMM rewrites psum only after this layer's scan_apply completed (in-order stream).
    char* ws = (char*)d_ws;
    u16* act = (u16*)ws;                 ws += (size_t)M_DIM * H_DIM * 2;   // 67.1 MB
    u16* Wt0 = (u16*)ws;                 ws += (size_t)32768 * 2;           // 64 KB
    u16* Wtl = (u16*)ws;                 ws += (size_t)5 * 65536 * 2;       // 640 KB
    char* uni = ws;                      ws += (size_t)8 * 1024 * 1024;     // 8 MB union
    float2* psum = (float2*)uni;                                            // 4 MB
    float* ca  = (float*)uni;                                               // 2 MB
    float* cb  = ca + (size_t)NC * S_DIM;                                   // 2 MB
    float* cc  = cb + (size_t)NC * S_DIM;                                   // 2 MB
    float* hin = cc + (size_t)NC * S_DIM;                                   // 2 MB
    float2* p2 = (float2*)ws;            ws += (size_t)64 * 256 * 8;        // 128 KB
    float* af  = (float*)ws;             ws += H_DIM * 4;
    float* shf = (float*)ws;             ws += H_DIM * 4;

    wt_convert_all<<<176, 256, 0, stream>>>(W0, Wl, Wt0, Wtl);

    const dim3 gscan(S_DIM / 64, NC / 4);
    for (int l = 0; l < L_DIM; ++l) {
        if (l == 0) {
            gemm_mfma<I_DIM, true><<<M_DIM / 64, 256, 0, stream>>>(x, Wt0, b0, act, psum);
        } else {
            gemm_mfma<H_DIM, false><<<M_DIM / 64, 256, 0, stream>>>(
                act, Wtl + (size_t)(l - 1) * 65536, bl + (size_t)(l - 1) * H_DIM, act, psum);
        }
        bn_reduce1<<<64, 256, 0, stream>>>(psum, p2);
        bn_finalize<<<1, 256, 0, stream>>>(p2, gamma + l * H_DIM, beta + l * H_DIM, af, shf);
        scan_compose<<<gscan, 256, 0, stream>>>(act, af, shf, u + l * H_DIM, ca, cb, cc);
        scan_prefix<<<S_DIM / 64, 64, 0, stream>>>(ca, cb, cc, hin);
        scan_apply<<<gscan, 256, 0, stream>>>(act, af, shf, u + l * H_DIM, hin);
    }
    classifier<<<B_DIM, 128, 0, stream>>>(act + (size_t)(T_DIM - 1) * S_DIM, Wc, bc, out);
}